// Round 14
// baseline (214.113 us; speedup 1.0000x reference)
//
#include <hip/hip_runtime.h>
#include <hip/hip_bf16.h>
#include <cstdint>
#include <cstddef>

// Problem constants
#define B_   2
#define S_   2048
#define H_   1024
#define NH   16
#define DH   64
#define LOG2E 1.4426950408889634f
#define SCALE2 (0.125f * LOG2E)   // D^-0.5 * log2(e): softmax done in exp2 domain

typedef __hip_bfloat16 bf16;
typedef short bf16x8 __attribute__((ext_vector_type(8)));   // 8 bf16 in 4 VGPRs
typedef float f32x4 __attribute__((ext_vector_type(4)));
typedef float f32x16 __attribute__((ext_vector_type(16)));

#define MFMA16(a, b, c) __builtin_amdgcn_mfma_f32_16x16x32_bf16((a), (b), (c), 0, 0, 0)
#define MFMA32(a, b, c) __builtin_amdgcn_mfma_f32_32x32x16_bf16((a), (b), (c), 0, 0, 0)

__device__ __forceinline__ void async16(const void* g, void* l) {
  __builtin_amdgcn_global_load_lds(
      (const __attribute__((address_space(1))) void*)g,
      (__attribute__((address_space(3))) void*)l,
      16, 0, 0);
}

// ---------------------------------------------------------------------------
// Fused prep kernel (one dispatch, grid 8208):
//  blocks [0,4096):     convert x f32->bf16; i=(L*256+tid)*4 (R5-proven)
//  blocks [4096,7168):  transpose+convert qkv [1024][3072] -> [3072][1024]
//  blocks [7168,8192):  transpose+convert out_w [1024][1024] -> [1024][1024]
//  blocks [8192,8208):  rpe cumsum * LOG2E (exp2-domain bias)
// ---------------------------------------------------------------------------
__device__ __forceinline__ void tr_body(const float* __restrict__ src,
                                        bf16* __restrict__ dst, int R, int C,
                                        int c0, int r0, bf16 (*tile)[33], int tid) {
  int tx = tid & 31, ty = tid >> 5;   // 32 x 8
  for (int i = 0; i < 32; i += 8)
    tile[ty + i][tx] = __float2bfloat16(src[(size_t)(r0 + ty + i) * C + c0 + tx]);
  __syncthreads();
  for (int i = 0; i < 32; i += 8)
    dst[(size_t)(c0 + ty + i) * R + r0 + tx] = tile[tx][ty + i];
}

__global__ __launch_bounds__(256)
void prep(const float* __restrict__ x, bf16* __restrict__ xb,
          const float* __restrict__ qkv, bf16* __restrict__ qkvT,
          const float* __restrict__ outw, bf16* __restrict__ outwT,
          const float* __restrict__ rpe, float* __restrict__ cum) {
  __shared__ char pm[2176] __attribute__((aligned(16)));
  const int L = blockIdx.x, tid = threadIdx.x;
  if (L < 4096) {
    int i = (L * 256 + tid) * 4;
    float4 v = *(const float4*)(x + i);
    bf16 o[4] = {__float2bfloat16(v.x), __float2bfloat16(v.y),
                 __float2bfloat16(v.z), __float2bfloat16(v.w)};
    *(uint64_t*)(xb + i) = *(const uint64_t*)o;
  } else if (L < 7168) {
    int t = L - 4096;
    int cx = t % 96, ry = t / 96;
    tr_body(qkv, qkvT, 1024, 3072, cx * 32, ry * 32, (bf16(*)[33])pm, tid);
  } else if (L < 8192) {
    int t = L - 7168;
    int cx = t & 31, ry = t >> 5;
    tr_body(outw, outwT, 1024, 1024, cx * 32, ry * 32, (bf16(*)[33])pm, tid);
  } else {
    // rpe cumsum (scaled by LOG2E)
    float* ssum = (float*)pm;
    int n = L - 8192;
    float loc[8];
    float s = 0.f;
    int base = tid * 8;
#pragma unroll
    for (int u = 0; u < 8; ++u) {
      loc[u] = rpe[n * S_ + base + u];
      s += loc[u];
    }
    ssum[tid] = s;
    __syncthreads();
    float own = s;
    for (int off = 1; off < 256; off <<= 1) {
      float v = (tid >= off) ? ssum[tid - off] : 0.f;
      __syncthreads();
      ssum[tid] += v;
      __syncthreads();
    }
    float run = ssum[tid] - own;   // exclusive prefix of this thread's chunk
#pragma unroll
    for (int u = 0; u < 8; ++u) {
      run += loc[u];
      cum[n * S_ + base + u] = run * LOG2E;
    }
  }
}

// ---------------------------------------------------------------------------
// GEMM: C[M x Nc] = A[M x 1024] * Bt[Nc x 1024]^T, bf16 in, f32 acc.
// 128x128 tile, BK=32, 256 threads (4 waves, 2x2 of 64x64).
// XOR-swizzled LDS (chunk c at slot c ^ ((row>>1)&3)) -> 2-way reads (free).
// MODE 0: epilogue re-layouts each wave's 64x64 tile through wave-private LDS
//   then b128 stores: q,k as [bn][s][d], V TRANSPOSED as [bn][d][s].
//   bounds(256,3): 768 blocks = 3/CU exactly -> no dispatch tail.
// MODE 1: f32 store to F0, row stride 1024;  Nc=1024 (256 blocks = 1/CU).
// ---------------------------------------------------------------------------
template <int MODE>
__global__ __launch_bounds__(256, MODE == 0 ? 3 : 2)
void gemm_bt(const bf16* __restrict__ A, const bf16* __restrict__ Bt,
             bf16* __restrict__ C0, bf16* __restrict__ C1, bf16* __restrict__ C2,
             float* __restrict__ F0) {
  __shared__ char smem[MODE == 0 ? 36864 : 16384] __attribute__((aligned(16)));
  bf16* As = (bf16*)smem;              // [128*32]
  bf16* Bs = (bf16*)(smem + 8192);     // [128*32]
  const int tid = threadIdx.x, lane = tid & 63, w = tid >> 6;
  const int lr = lane & 15, lq = lane >> 4;
  const int m0 = blockIdx.y * 128, n0 = blockIdx.x * 128;
  const int wm = (w & 1) * 64, wn = (w >> 1) * 64;

  f32x4 acc[4][4] = {};

  for (int k0 = 0; k0 < 1024; k0 += 32) {
    __syncthreads();
    for (int t = 0; t < 2; ++t) {
      int c = (t * 4 + w) * 64 + lane;          // 16B-chunk id 0..511
      int row = c >> 2, ch = c & 3;
      int k8 = (ch ^ ((row >> 1) & 3)) * 8;     // swizzled source chunk
      async16(A + (size_t)(m0 + row) * 1024 + k0 + k8,
              (char*)As + (size_t)(t * 4 + w) * 1024 + lane * 16);
      async16(Bt + (size_t)(n0 + row) * 1024 + k0 + k8,
              (char*)Bs + (size_t)(t * 4 + w) * 1024 + lane * 16);
    }
    __syncthreads();
    bf16x8 af[4], bfr[4];
#pragma unroll
    for (int mt = 0; mt < 4; ++mt) {
      int row = wm + mt * 16 + lr;
      af[mt] = *(const bf16x8*)(As + row * 32 + ((lq ^ ((row >> 1) & 3)) << 3));
    }
#pragma unroll
    for (int nt = 0; nt < 4; ++nt) {
      int row = wn + nt * 16 + lr;
      bfr[nt] = *(const bf16x8*)(Bs + row * 32 + ((lq ^ ((row >> 1) & 3)) << 3));
    }
#pragma unroll
    for (int mt = 0; mt < 4; ++mt)
#pragma unroll
      for (int nt = 0; nt < 4; ++nt)
        acc[mt][nt] = MFMA16(af[mt], bfr[nt], acc[mt][nt]);
  }

  if (MODE == 0) {
    __syncthreads();   // all As/Bs reads done; reuse LDS for epilogue tiles
    bf16* E = (bf16*)smem + w * (64 * 72);   // wave-private [64][72]
    const int cbase = n0 + wn;               // 64-aligned
    const int mm = cbase >> 10, nn = (cbase >> 6) & 15;
    const int bb = (m0 + wm) >> 11;
    const int sbase = (m0 + wm) & 2047;
    if (mm < 2) {
      // write acc as [s][d] into E
#pragma unroll
      for (int mt = 0; mt < 4; ++mt)
#pragma unroll
        for (int nt = 0; nt < 4; ++nt)
#pragma unroll
          for (int r = 0; r < 4; ++r)
            E[(mt * 16 + lq * 4 + r) * 72 + nt * 16 + lr] =
                __float2bfloat16(acc[mt][nt][r]);
      // wave-private readback (in-wave lgkm ordering), b128 stores
      bf16* dst = (mm == 0 ? C0 : C1) +
                  ((size_t)(bb * NH + nn) * S_ + sbase) * DH;
#pragma unroll
      for (int it = 0; it < 8; ++it) {
        int c = it * 64 + lane;
        int rw = c >> 3, c8 = c & 7;
        *(uint4*)(dst + (size_t)rw * DH + c8 * 8) =
            *(const uint4*)(E + rw * 72 + c8 * 8);
      }
    } else {
      // V: write acc as [d][s] into E
#pragma unroll
      for (int mt = 0; mt < 4; ++mt)
#pragma unroll
        for (int nt = 0; nt < 4; ++nt)
#pragma unroll
          for (int r = 0; r < 4; ++r)
            E[(nt * 16 + lr) * 72 + mt * 16 + lq * 4 + r] =
                __float2bfloat16(acc[mt][nt][r]);
      bf16* dst = C2 + (size_t)(bb * NH + nn) * DH * S_;
#pragma unroll
      for (int it = 0; it < 8; ++it) {
        int c = it * 64 + lane;
        int dr = c >> 3, c8 = c & 7;
        *(uint4*)(dst + (size_t)dr * S_ + sbase + c8 * 8) =
            *(const uint4*)(E + dr * 72 + c8 * 8);
      }
    }
  } else {
#pragma unroll
    for (int mt = 0; mt < 4; ++mt)
#pragma unroll
      for (int nt = 0; nt < 4; ++nt)
#pragma unroll
        for (int r = 0; r < 4; ++r) {
          int rM = m0 + wm + mt * 16 + lq * 4 + r;
          int cN = n0 + wn + nt * 16 + lr;
          F0[(size_t)rM * 1024 + cN] = acc[mt][nt][r];
        }
  }
}

// ---------------------------------------------------------------------------
// Flash attention, 32x32x16 MFMA version (halves LDS fragment traffic, the
// measured bottleneck: DS-pipe ~671 cyc/wave-iter vs MFMA ~175 at R13).
// No-max exp2 softmax (R13-verified). Bias via 4 phase-shifted cum-window
// copies -> one ds_read_b128 per reg-quad instead of 4 ds_read_b32.
//
// Layouts (mfma_f32_32x32x16_bf16):
//   A[m][k]: m = lane&31, k = (lane>>5)*8 + u   (8 bf16 = b128)
//   B[k][n]: n = lane&31, k = (lane>>5)*8 + u
//   C[m][n]: n = lane&31, m = (reg&3) + 8*(reg>>2) + 4*(lane>>5), reg 0..15
//
// QK: S^T[128 j][64 i] = K·Q^T; 8 tiles 32x32; wave w owns i-block (w&1)*32,
//     j-blocks (w>>1)*64 + {0,32}. Lane owns ONE i = ib + (lane&31).
// P[64 i][128 j] in LDS (swizzled chunk c ^ (row&15)); rows are written by
//     TWO waves (j-halves) -> 3rd barrier before PV.
// PV: O[64 i][64 d]; wave w owns tile (ib=(w&1)*32, db=(w>>1)*32); K-dim j=128
//     -> 8 MFMAs; lacc = MFMA(pf, ones) shares the pf reads.
// LDS: K [0,16384) [128j][64d] sw ^(row&7); V [16384,32768) [64d][128j] sw
//     ^(row&15); Ps [32768,49152); cumS 4x192 f32 [49152,52224). 3 blocks/CU.
// ---------------------------------------------------------------------------
__global__ __launch_bounds__(256, 3)
void fa_kernel(const bf16* __restrict__ q, const bf16* __restrict__ k,
               const bf16* __restrict__ vt, const float* __restrict__ cum,
               bf16* __restrict__ mix) {
  __shared__ char smem[52224] __attribute__((aligned(16)));
  float* cumS = (float*)(smem + 49152);         // [4][192]

  const int tid = threadIdx.x, lane = tid & 63, w = tid >> 6;  // w: 0..3
  const int l31 = lane & 31, lh = lane >> 5;

  const int L = blockIdx.x;
  const int xcd = L & 7, slot = L >> 3;
  const int bn = xcd + 8 * (slot >> 5);         // 4 heads per XCD
  const int ti = 31 - (slot & 31);              // descending work
  const int n = bn & (NH - 1);
  const int b = bn >> 4;
  const float* cumn = cum + n * S_;

  const int i0 = ti * 64;
  const int nj = (ti >> 1) + 1;                 // KV tiles (128 cols each)

  const int ib = (w & 1) * 32;                  // i-block (QK cols, O rows)
  const int db = (w >> 1) * 32;                 // d-block (O cols)
  const int jbw = (w >> 1) * 64;                // j-block base (QK rows)
  const int iloc = ib + l31;                    // this lane's Q row in tile

  // Q B-frag: B[k=d][n=i]; lane holds i = iloc, d = dc*16 + lh*8 + u
  const bf16* qrow = q + ((size_t)bn * S_ + i0 + iloc) * DH;
  bf16x8 qf[4];
#pragma unroll
  for (int dc = 0; dc < 4; ++dc)
    qf[dc] = *(const bf16x8*)(qrow + dc * 16 + lh * 8);

  // all-ones B fragment for the l row-sum MFMA
  bf16x8 ones;
#pragma unroll
  for (int u = 0; u < 8; ++u) ones[u] = (short)0x3F80;

  f32x16 oacc = {};
  f32x16 lacc = {};

  for (int jt = 0; jt < nj; ++jt) {
    const int j0 = jt * 128;
    const bool diag = (jt == nj - 1);
    const int doff = i0 - j0;                   // 0 or 64 on diagonal tile
    __syncthreads();   // prior iter's K/V/cum reads done; regions free

    // stage K tile [128 j][64 d], slot (row, s) holds chunk s^(row&7)
    const char* ksrc = (const char*)(k + ((size_t)bn * S_ + j0) * DH);
#pragma unroll
    for (int t = 0; t < 4; ++t) {
      int cb = t * 4 + w;
      int row = cb * 8 + (lane >> 3);
      int cs = (lane & 7) ^ (row & 7);
      async16(ksrc + row * 128 + cs * 16, smem + cb * 1024 + lane * 16);
    }
    // stage Vt tile [64 d][128 j], slot (row, s) holds chunk s^(row&15)
    const char* vsrc = (const char*)(vt + (size_t)bn * DH * S_);
#pragma unroll
    for (int t = 0; t < 4; ++t) {
      int cb = t * 4 + w;
      int row = cb * 4 + (lane >> 4);          // d index 0..63
      int cs = (lane & 15) ^ (row & 15);
      async16(vsrc + (size_t)row * (S_ * 2) + j0 * 2 + cs * 16,
              smem + 16384 + cb * 1024 + lane * 16);
    }
    // stage 4 phase-shifted cum windows: cumS[p][t] = win[t+p],
    // win[t] = cumn[clamp(i0-j0-127+t)]
    if (tid < 192) {
      int base = i0 - j0 - 127 + tid;
#pragma unroll
      for (int p = 0; p < 4; ++p) {
        int src = base + p;
        src = src < 0 ? 0 : (src > S_ - 1 ? S_ - 1 : src);
        cumS[p * 192 + tid] = cumn[src];
      }
    }
    __syncthreads();   // staging complete

    // S^T = K * Q^T: 2 tiles per wave (j-blocks jbw, jbw+32; i-block ib)
    f32x16 sa2[2] = {};
#pragma unroll
    for (int dc = 0; dc < 4; ++dc)
#pragma unroll
      for (int t32 = 0; t32 < 2; ++t32) {
        int row = jbw + t32 * 32 + l31;        // j row
        bf16x8 kf = *(const bf16x8*)(smem + row * 128 +
                        (((dc * 2 + lh) ^ (row & 7)) << 4));
        sa2[t32] = MFMA32(kf, qf[dc], sa2[t32]);
      }

    // p = exp2(s*SCALE2 + cum[i-j]); write P[64][128] swizzled b64 quads.
    // reg r of tile t32: j = jbw + t32*32 + (r>>2)*8 + lh*4 + (r&3)
    if (!diag) {
#pragma unroll
      for (int t32 = 0; t32 < 2; ++t32)
#pragma unroll
        for (int qq = 0; qq < 4; ++qq) {
          int jl = jbw + t32 * 32 + qq * 8 + lh * 4;
          int Xm3 = 124 + iloc - jl;           // window idx of m=3 elem
          int p = Xm3 & 3, b0 = Xm3 & ~3;
          f32x4 cv = *(const f32x4*)(cumS + p * 192 + b0);  // win[Xm3..Xm3+3]
          bf16 pk[4];
#pragma unroll
          for (int m = 0; m < 4; ++m)
            pk[m] = __float2bfloat16(
                exp2f(sa2[t32][qq * 4 + m] * SCALE2 + cv[3 - m]));
          int c = (jbw >> 3) + t32 * 4 + qq;   // 16B-chunk, lh = half
          *(uint64_t*)(smem + 32768 + iloc * 256 +
                       ((c ^ (iloc & 15)) << 4) + lh * 8) = *(const uint64_t*)pk;
        }
    } else {
#pragma unroll
      for (int t32 = 0; t32 < 2; ++t32)
#pragma unroll
        for (int qq = 0; qq < 4; ++qq) {
          int jl = jbw + t32 * 32 + qq * 8 + lh * 4;
          int Xm3 = 124 + iloc - jl;
          int p = Xm3 & 3, b0 = Xm3 & ~3;
          f32x4 cv = *(const f32x4*)(cumS + p * 192 + b0);
          bf16 pk[4];
#pragma unroll
          for (int m = 0; m < 4; ++m) {
            float pv = (doff + iloc - jl - m >= 0)
                           ? exp2f(sa2[t32][qq * 4 + m] * SCALE2 + cv[3 - m])
                           : 0.f;
            pk[m] = __float2bfloat16(pv);
          }
          int c = (jbw >> 3) + t32 * 4 + qq;
          *(uint64_t*)(smem + 32768 + iloc * 256 +
                       ((c ^ (iloc & 15)) << 4) + lh * 8) = *(const uint64_t*)pk;
        }
    }

    __syncthreads();   // P complete (rows span waves) before PV reads

    // O += P V; l += P 1.  Wave tile: rows ib..ib+31, cols db..db+31.
#pragma unroll
    for (int kc = 0; kc < 8; ++kc) {
      int rr = ib + l31;                       // P row = i
      bf16x8 pf = *(const bf16x8*)(smem + 32768 + rr * 256 +
                      (((kc * 2 + lh) ^ (rr & 15)) << 4));
      lacc = MFMA32(pf, ones, lacc);
      int dd = db + l31;                       // V col = d (Vs row)
      bf16x8 vf = *(const bf16x8*)(smem + 16384 + dd * 256 +
                      (((kc * 2 + lh) ^ (dd & 15)) << 4));
      oacc = MFMA32(pf, vf, oacc);
    }
  }

  // epilogue: mix[b][s][n][d]; C-layout row m = (r&3)+8*(r>>2)+4*lh, col = l31
#pragma unroll
  for (int r = 0; r < 16; ++r) {
    int i = i0 + ib + (r & 3) + 8 * (r >> 2) + 4 * lh;
    int d = db + l31;
    mix[((size_t)(b * S_ + i) * NH + n) * DH + d] =
        __float2bfloat16(oacc[r] / lacc[r]);
  }
}

// ---------------------------------------------------------------------------
extern "C" void kernel_launch(void* const* d_in, const int* in_sizes, int n_in,
                              void* d_out, int out_size, void* d_ws, size_t ws_size,
                              hipStream_t stream) {
  const float* x     = (const float*)d_in[0];   // [B,S,H] f32
  const float* qkv   = (const float*)d_in[1];   // [H,3,N,D] f32 == [1024][3072]
  const float* out_w = (const float*)d_in[2];   // [N,D,H] f32   == [1024][1024]
  const float* rpe   = (const float*)d_in[3];   // [N,S] f32
  float* out = (float*)d_out;                   // [B,S,H] f32

  char* ws = (char*)d_ws;
  bf16* qkvT  = (bf16*)(ws + 0);          // [3072][1024] bf16   6291456 B
  bf16* outwT = (bf16*)(ws + 6291456);    // [1024][1024] bf16   2097152 B
  bf16* xb    = (bf16*)(ws + 8388608);    // [4096][1024] bf16   8388608 B
  bf16* qb    = (bf16*)(ws + 16777216);   // [bn][S][D]          8388608 B
  bf16* kb    = (bf16*)(ws + 25165824);   // [bn][S][D]          8388608 B
  bf16* vtb   = (bf16*)(ws + 33554432);   // [bn][D][S]          8388608 B
  bf16* mixb  = (bf16*)(ws + 41943040);   // [b][s][n][d]        8388608 B
  float* cum  = (float*)(ws + 50331648);  // [N][S] f32 (xLOG2E)  131072 B

  // 1. fused prep: convert x, transpose+convert weights, rpe cumsum
  prep<<<8208, 256, 0, stream>>>(x, xb, qkv, qkvT, out_w, outwT, rpe, cum);
  // 2. QKV projection (V written pre-transposed; 768 blocks = 3/CU, no tail)
  gemm_bt<0><<<dim3(3072 / 128, 4096 / 128), 256, 0, stream>>>(xb, qkvT, qb, kb, vtb, nullptr);
  // 3. attention (32x32x16 MFMA, no-max exp2 softmax, MFMA row sums)
  fa_kernel<<<1024, 256, 0, stream>>>(qb, kb, vtb, cum, mixb);
  // 4. output projection (f32 out)
  gemm_bt<1><<<dim3(1024 / 128, 4096 / 128), 256, 0, stream>>>(mixb, outwT, nullptr, nullptr, nullptr, out);
}

// Round 15
// 188.715 us; speedup vs baseline: 1.1346x; 1.1346x over previous
//
#include <hip/hip_runtime.h>
#include <hip/hip_bf16.h>
#include <cstdint>
#include <cstddef>

// Problem constants
#define B_   2
#define S_   2048
#define H_   1024
#define NH   16
#define DH   64
#define LOG2E 1.4426950408889634f
#define SCALE2 (0.125f * LOG2E)   // D^-0.5 * log2(e): softmax done in exp2 domain

typedef __hip_bfloat16 bf16;
typedef short bf16x8 __attribute__((ext_vector_type(8)));   // 8 bf16 in 4 VGPRs
typedef float f32x4 __attribute__((ext_vector_type(4)));

#define MFMA16(a, b, c) __builtin_amdgcn_mfma_f32_16x16x32_bf16((a), (b), (c), 0, 0, 0)

__device__ __forceinline__ void async16(const void* g, void* l) {
  __builtin_amdgcn_global_load_lds(
      (const __attribute__((address_space(1))) void*)g,
      (__attribute__((address_space(3))) void*)l,
      16, 0, 0);
}

// ---------------------------------------------------------------------------
// Fused prep kernel (one dispatch, grid 8208):
//  blocks [0,4096):     convert x f32->bf16; i=(L*256+tid)*4 (R5-proven)
//  blocks [4096,7168):  transpose+convert qkv [1024][3072] -> [3072][1024]
//  blocks [7168,8192):  transpose+convert out_w [1024][1024] -> [1024][1024]
//  blocks [8192,8208):  rpe cumsum * LOG2E (exp2-domain bias)
// ---------------------------------------------------------------------------
__device__ __forceinline__ void tr_body(const float* __restrict__ src,
                                        bf16* __restrict__ dst, int R, int C,
                                        int c0, int r0, bf16 (*tile)[33], int tid) {
  int tx = tid & 31, ty = tid >> 5;   // 32 x 8
  for (int i = 0; i < 32; i += 8)
    tile[ty + i][tx] = __float2bfloat16(src[(size_t)(r0 + ty + i) * C + c0 + tx]);
  __syncthreads();
  for (int i = 0; i < 32; i += 8)
    dst[(size_t)(c0 + ty + i) * R + r0 + tx] = tile[tx][ty + i];
}

__global__ __launch_bounds__(256)
void prep(const float* __restrict__ x, bf16* __restrict__ xb,
          const float* __restrict__ qkv, bf16* __restrict__ qkvT,
          const float* __restrict__ outw, bf16* __restrict__ outwT,
          const float* __restrict__ rpe, float* __restrict__ cum) {
  __shared__ char pm[2176] __attribute__((aligned(16)));
  const int L = blockIdx.x, tid = threadIdx.x;
  if (L < 4096) {
    int i = (L * 256 + tid) * 4;
    float4 v = *(const float4*)(x + i);
    bf16 o[4] = {__float2bfloat16(v.x), __float2bfloat16(v.y),
                 __float2bfloat16(v.z), __float2bfloat16(v.w)};
    *(uint64_t*)(xb + i) = *(const uint64_t*)o;
  } else if (L < 7168) {
    int t = L - 4096;
    int cx = t % 96, ry = t / 96;
    tr_body(qkv, qkvT, 1024, 3072, cx * 32, ry * 32, (bf16(*)[33])pm, tid);
  } else if (L < 8192) {
    int t = L - 7168;
    int cx = t & 31, ry = t >> 5;
    tr_body(outw, outwT, 1024, 1024, cx * 32, ry * 32, (bf16(*)[33])pm, tid);
  } else {
    // rpe cumsum (scaled by LOG2E)
    float* ssum = (float*)pm;
    int n = L - 8192;
    float loc[8];
    float s = 0.f;
    int base = tid * 8;
#pragma unroll
    for (int u = 0; u < 8; ++u) {
      loc[u] = rpe[n * S_ + base + u];
      s += loc[u];
    }
    ssum[tid] = s;
    __syncthreads();
    float own = s;
    for (int off = 1; off < 256; off <<= 1) {
      float v = (tid >= off) ? ssum[tid - off] : 0.f;
      __syncthreads();
      ssum[tid] += v;
      __syncthreads();
    }
    float run = ssum[tid] - own;   // exclusive prefix of this thread's chunk
#pragma unroll
    for (int u = 0; u < 8; ++u) {
      run += loc[u];
      cum[n * S_ + base + u] = run * LOG2E;
    }
  }
}

// ---------------------------------------------------------------------------
// GEMM: C[M x Nc] = A[M x 1024] * Bt[Nc x 1024]^T, bf16 in, f32 acc.
// 256 threads (4 waves). XOR-swizzled LDS -> 2-way reads (free).
// MODE 0: 128x128 tile (NT=4). Epilogue re-layouts each wave's 64x64 tile
//   through wave-private LDS then b128 stores: q,k as [bn][s][d], V
//   TRANSPOSED as [bn][d][s]. bounds(256,3): 768 blocks = 3/CU, no tail.
// MODE 1: 128x64 tile (NT=2), grid (16,32)=512 blocks = 2/CU (was 1/CU at
//   128x128 — every barrier drain exposed). f32 store to F0, row stride 1024.
// ---------------------------------------------------------------------------
template <int MODE>
__global__ __launch_bounds__(256, MODE == 0 ? 3 : 2)
void gemm_bt(const bf16* __restrict__ A, const bf16* __restrict__ Bt,
             bf16* __restrict__ C0, bf16* __restrict__ C1, bf16* __restrict__ C2,
             float* __restrict__ F0) {
  constexpr int NT = (MODE == 0) ? 4 : 2;     // n-subtiles per wave
  constexpr int NB = NT * 32;                 // block n-extent: 128 or 64
  __shared__ char smem[MODE == 0 ? 36864 : 12288] __attribute__((aligned(16)));
  bf16* As = (bf16*)smem;              // [128*32]
  bf16* Bs = (bf16*)(smem + 8192);     // [NB*32]
  const int tid = threadIdx.x, lane = tid & 63, w = tid >> 6;
  const int lr = lane & 15, lq = lane >> 4;
  const int m0 = blockIdx.y * 128, n0 = blockIdx.x * NB;
  const int wm = (w & 1) * 64, wn = (w >> 1) * (NT * 16);

  f32x4 acc[4][NT] = {};

  for (int k0 = 0; k0 < 1024; k0 += 32) {
    __syncthreads();
#pragma unroll
    for (int t = 0; t < 2; ++t) {
      int c = (t * 4 + w) * 64 + lane;          // 16B-chunk id 0..511
      int row = c >> 2, ch = c & 3;
      int k8 = (ch ^ ((row >> 1) & 3)) * 8;     // swizzled source chunk
      async16(A + (size_t)(m0 + row) * 1024 + k0 + k8,
              (char*)As + (size_t)(t * 4 + w) * 1024 + lane * 16);
    }
#pragma unroll
    for (int t = 0; t < NB / 64; ++t) {
      int c = (t * 4 + w) * 64 + lane;          // chunk id, NB*4 total
      int row = c >> 2, ch = c & 3;
      int k8 = (ch ^ ((row >> 1) & 3)) * 8;
      async16(Bt + (size_t)(n0 + row) * 1024 + k0 + k8,
              (char*)Bs + (size_t)(t * 4 + w) * 1024 + lane * 16);
    }
    __syncthreads();
    bf16x8 af[4], bfr[NT];
#pragma unroll
    for (int mt = 0; mt < 4; ++mt) {
      int row = wm + mt * 16 + lr;
      af[mt] = *(const bf16x8*)(As + row * 32 + ((lq ^ ((row >> 1) & 3)) << 3));
    }
#pragma unroll
    for (int nt = 0; nt < NT; ++nt) {
      int row = wn + nt * 16 + lr;
      bfr[nt] = *(const bf16x8*)(Bs + row * 32 + ((lq ^ ((row >> 1) & 3)) << 3));
    }
#pragma unroll
    for (int mt = 0; mt < 4; ++mt)
#pragma unroll
      for (int nt = 0; nt < NT; ++nt)
        acc[mt][nt] = MFMA16(af[mt], bfr[nt], acc[mt][nt]);
  }

  if (MODE == 0) {
    __syncthreads();   // all As/Bs reads done; reuse LDS for epilogue tiles
    bf16* E = (bf16*)smem + w * (64 * 72);   // wave-private [64][72]
    const int cbase = n0 + wn;               // 64-aligned
    const int mm = cbase >> 10, nn = (cbase >> 6) & 15;
    const int bb = (m0 + wm) >> 11;
    const int sbase = (m0 + wm) & 2047;
    if (mm < 2) {
      // write acc as [s][d] into E
#pragma unroll
      for (int mt = 0; mt < 4; ++mt)
#pragma unroll
        for (int nt = 0; nt < 4; ++nt)
#pragma unroll
          for (int r = 0; r < 4; ++r)
            E[(mt * 16 + lq * 4 + r) * 72 + nt * 16 + lr] =
                __float2bfloat16(acc[mt][nt][r]);
      // wave-private readback (in-wave lgkm ordering), b128 stores
      bf16* dst = (mm == 0 ? C0 : C1) +
                  ((size_t)(bb * NH + nn) * S_ + sbase) * DH;
#pragma unroll
      for (int it = 0; it < 8; ++it) {
        int c = it * 64 + lane;
        int rw = c >> 3, c8 = c & 7;
        *(uint4*)(dst + (size_t)rw * DH + c8 * 8) =
            *(const uint4*)(E + rw * 72 + c8 * 8);
      }
    } else {
      // V: write acc as [d][s] into E
#pragma unroll
      for (int mt = 0; mt < 4; ++mt)
#pragma unroll
        for (int nt = 0; nt < 4; ++nt)
#pragma unroll
          for (int r = 0; r < 4; ++r)
            E[(nt * 16 + lr) * 72 + mt * 16 + lq * 4 + r] =
                __float2bfloat16(acc[mt][nt][r]);
      bf16* dst = C2 + (size_t)(bb * NH + nn) * DH * S_;
#pragma unroll
      for (int it = 0; it < 8; ++it) {
        int c = it * 64 + lane;
        int dr = c >> 3, c8 = c & 7;
        *(uint4*)(dst + (size_t)dr * S_ + sbase + c8 * 8) =
            *(const uint4*)(E + dr * 72 + c8 * 8);
      }
    }
  } else {
#pragma unroll
    for (int mt = 0; mt < 4; ++mt)
#pragma unroll
      for (int nt = 0; nt < NT; ++nt)
#pragma unroll
        for (int r = 0; r < 4; ++r) {
          int rM = m0 + wm + mt * 16 + lq * 4 + r;
          int cN = n0 + wn + nt * 16 + lr;
          F0[(size_t)rM * 1024 + cN] = acc[mt][nt][r];
        }
  }
}

// ---------------------------------------------------------------------------
// Flash attention (R13 16x16 structure — R14's 32x32 restructure tripled
// bank conflicts + HBM writes and regressed; reverted). No-max exp2 softmax
// (R13-verified), MFMA row sums.
// NEW vs R13: bias via 4 phase-shifted cum-window copies (R14-verified
// addressing) -> one ds_read_b128 per reg-quad instead of 4 ds_read_b32
// (cuts ~140 of ~670 DS cyc/wave-iter — fa is DS-pipe-bound).
// q,k: [bn][S][D] bf16;  vt: [bn][D][S] bf16;  cum: [N][S] f32 (xLOG2E);
// mix out: [b][s][n][d] bf16
// 1D grid 1024, block 256 (4 waves). xcd=L&7 pins 4 heads per XCD; ti
// descends with L. One 64-row Q-tile per block; nj=(ti>>1)+1 KV-tile iters.
// S^T trick: compute S^T = K*Q^T so each lane owns ONE softmax row.
// LDS: K [0,16384); V [16384,32768); Ps[64][136] [32768,50176);
// cumS[4][192] f32 [50176,53248). 53248*3 = 159744 <= 160 KB -> 3 blocks/CU.
// ---------------------------------------------------------------------------
__global__ __launch_bounds__(256, 3)
void fa_kernel(const bf16* __restrict__ q, const bf16* __restrict__ k,
               const bf16* __restrict__ vt, const float* __restrict__ cum,
               bf16* __restrict__ mix) {
  __shared__ char smem[53248] __attribute__((aligned(16)));
  bf16* Ps = (bf16*)(smem + 32768);             // [64][136]
  float* cumS = (float*)(smem + 50176);         // [4][192]

  const int tid = threadIdx.x, lane = tid & 63, w = tid >> 6;  // w: 0..3
  const int lr = lane & 15, lq = lane >> 4;

  const int L = blockIdx.x;
  const int xcd = L & 7, slot = L >> 3;
  const int bn = xcd + 8 * (slot >> 5);         // 4 heads per XCD
  const int ti = 31 - (slot & 31);              // descending work
  const int n = bn & (NH - 1);
  const int b = bn >> 4;
  const float* cumn = cum + n * S_;

  const int i0 = ti * 64;
  const int nj = (ti >> 1) + 1;                 // KV tiles (128 cols each)

  // Q fragments (B-operand for S^T = K*Q^T): lane n=lr reads Q row lr
  const bf16* qbase = q + ((size_t)bn * S_ + i0 + w * 16) * DH;
  bf16x8 qf[2];
#pragma unroll
  for (int kt = 0; kt < 2; ++kt)
    qf[kt] = *(const bf16x8*)(qbase + lr * DH + kt * 32 + lq * 8);

  // all-ones B fragment for the l row-sum MFMA
  bf16x8 ones;
#pragma unroll
  for (int u = 0; u < 8; ++u) ones[u] = (short)0x3F80;

  f32x4 oacc[4] = {};
  f32x4 lacc = {};                              // row sums, C-layout rows lq*4+r
  const int iloc = w * 16 + lr;

  for (int jt = 0; jt < nj; ++jt) {
    const int j0 = jt * 128;
    const bool diag = (jt == nj - 1);
    __syncthreads();   // prior K/V/cum reads done; regions free

    // stage K tile (swizzled: slot (row,c) holds global chunk c^(row&7))
    const char* ksrc = (const char*)(k + ((size_t)bn * S_ + j0) * DH);
#pragma unroll
    for (int t = 0; t < 4; ++t) {
      int cb = t * 4 + w;
      int row = cb * 8 + (lane >> 3);
      int cs = (lane & 7) ^ (row & 7);
      async16(ksrc + row * 128 + cs * 16, smem + cb * 1024 + lane * 16);
    }
    // stage Vt tile (swizzled: slot (row,c) holds global chunk c^(row&15))
    const char* vsrc = (const char*)(vt + (size_t)bn * DH * S_);
#pragma unroll
    for (int t = 0; t < 4; ++t) {
      int cb = t * 4 + w;
      int row = cb * 4 + (lane >> 4);          // d index 0..63
      int cs = (lane & 15) ^ (row & 15);
      async16(vsrc + (size_t)row * (S_ * 2) + j0 * 2 + cs * 16,
              smem + 16384 + cb * 1024 + lane * 16);
    }
    // stage 4 phase-shifted cum windows: cumS[p][t] = win[t+p],
    // win[t] = cumn[clamp(i0-j0-127+t)]  (R14-verified addressing)
    if (tid < 192) {
      int base = i0 - j0 - 127 + tid;
#pragma unroll
      for (int p = 0; p < 4; ++p) {
        int src = base + p;
        src = src < 0 ? 0 : (src > S_ - 1 ? S_ - 1 : src);
        cumS[p * 192 + tid] = cumn[src];
      }
    }
    __syncthreads();   // staging complete

    // S^T = K * Q^T: sa[nt][r] = S[i=i0+iloc][j = j0 + nt*16 + lq*4 + r]
    f32x4 sa[8] = {};
#pragma unroll
    for (int kt = 0; kt < 2; ++kt)
#pragma unroll
      for (int nt = 0; nt < 8; ++nt) {
        int krow = nt * 16 + lr;
        bf16x8 kf = *(const bf16x8*)(smem + krow * 128 +
                        (((kt * 4 + lq) ^ (krow & 7)) << 4));
        sa[nt] = MFMA16(kf, qf[kt], sa[nt]);
      }

    // p = exp2(s*SCALE2 + cum[i-j]) (no max subtraction), pack, write P.
    // Bias for the 4 descending rel values comes from ONE b128 read:
    // Xm3 = window idx at r=3; cv[m] = win[Xm3+m]; bias(r) = cv[3-r].
    const int doff = i0 - j0;     // 0 or 64 on diagonal tile
    if (!diag) {
#pragma unroll
      for (int nt = 0; nt < 8; ++nt) {
        int jl = nt * 16 + lq * 4;
        int Xm3 = 124 + iloc - jl;
        int p = Xm3 & 3, b0 = Xm3 & ~3;
        f32x4 cv = *(const f32x4*)(cumS + p * 192 + b0);
        bf16 pk[4];
#pragma unroll
        for (int r = 0; r < 4; ++r)
          pk[r] = __float2bfloat16(exp2f(sa[nt][r] * SCALE2 + cv[3 - r]));
        *(uint64_t*)(Ps + iloc * 136 + nt * 16 + lq * 4) = *(const uint64_t*)pk;
      }
    } else {
#pragma unroll
      for (int nt = 0; nt < 8; ++nt) {
        int jl = nt * 16 + lq * 4;
        int Xm3 = 124 + iloc - jl;
        int p = Xm3 & 3, b0 = Xm3 & ~3;
        f32x4 cv = *(const f32x4*)(cumS + p * 192 + b0);
        bf16 pk[4];
#pragma unroll
        for (int r = 0; r < 4; ++r) {
          float pv = (doff + iloc - jl - r >= 0)
                         ? exp2f(sa[nt][r] * SCALE2 + cv[3 - r])
                         : 0.f;
          pk[r] = __float2bfloat16(pv);
        }
        *(uint64_t*)(Ps + iloc * 136 + nt * 16 + lq * 4) = *(const uint64_t*)pk;
      }
    }

    // O += P V; l += P 1  (wave-private P rows; in-wave DS ordering suffices)
#pragma unroll
    for (int kt2 = 0; kt2 < 4; ++kt2) {
      bf16x8 pf = *(const bf16x8*)(Ps + (w * 16 + lr) * 136 + kt2 * 32 + lq * 8);
      lacc = MFMA16(pf, ones, lacc);
#pragma unroll
      for (int dt = 0; dt < 4; ++dt) {
        int vrow = dt * 16 + lr;
        bf16x8 vf = *(const bf16x8*)(smem + 16384 + vrow * 256 +
                        (((kt2 * 4 + lq) ^ (vrow & 15)) << 4));
        oacc[dt] = MFMA16(pf, vf, oacc[dt]);
      }
    }
  }

  // epilogue: mix[b][s][n][d]; lacc[r] is the row sum for row lq*4+r
#pragma unroll
  for (int dt = 0; dt < 4; ++dt)
#pragma unroll
    for (int r = 0; r < 4; ++r) {
      int i = i0 + w * 16 + lq * 4 + r;
      int d = dt * 16 + lr;
      mix[((size_t)(b * S_ + i) * NH + n) * DH + d] =
          __float2bfloat16(oacc[dt][r] / lacc[r]);
    }
}

// ---------------------------------------------------------------------------
extern "C" void kernel_launch(void* const* d_in, const int* in_sizes, int n_in,
                              void* d_out, int out_size, void* d_ws, size_t ws_size,
                              hipStream_t stream) {
  const float* x     = (const float*)d_in[0];   // [B,S,H] f32
  const float* qkv   = (const float*)d_in[1];   // [H,3,N,D] f32 == [1024][3072]
  const float* out_w = (const float*)d_in[2];   // [N,D,H] f32   == [1024][1024]
  const float* rpe   = (const float*)d_in[3];   // [N,S] f32
  float* out = (float*)d_out;                   // [B,S,H] f32

  char* ws = (char*)d_ws;
  bf16* qkvT  = (bf16*)(ws + 0);          // [3072][1024] bf16   6291456 B
  bf16* outwT = (bf16*)(ws + 6291456);    // [1024][1024] bf16   2097152 B
  bf16* xb    = (bf16*)(ws + 8388608);    // [4096][1024] bf16   8388608 B
  bf16* qb    = (bf16*)(ws + 16777216);   // [bn][S][D]          8388608 B
  bf16* kb    = (bf16*)(ws + 25165824);   // [bn][S][D]          8388608 B
  bf16* vtb   = (bf16*)(ws + 33554432);   // [bn][D][S]          8388608 B
  bf16* mixb  = (bf16*)(ws + 41943040);   // [b][s][n][d]        8388608 B
  float* cum  = (float*)(ws + 50331648);  // [N][S] f32 (xLOG2E)  131072 B

  // 1. fused prep: convert x, transpose+convert weights, rpe cumsum
  prep<<<8208, 256, 0, stream>>>(x, xb, qkv, qkvT, out_w, outwT, rpe, cum);
  // 2. QKV projection (V written pre-transposed; 768 blocks = 3/CU, no tail)
  gemm_bt<0><<<dim3(3072 / 128, 4096 / 128), 256, 0, stream>>>(xb, qkvT, qb, kb, vtb, nullptr);
  // 3. attention (R13 structure + b128 bias loads)
  fa_kernel<<<1024, 256, 0, stream>>>(qb, kb, vtb, cum, mixb);
  // 4. output projection (f32 out; 128x64 tiles -> 512 blocks = 2/CU)
  gemm_bt<1><<<dim3(1024 / 64, 4096 / 128), 256, 0, stream>>>(mixb, outwT, nullptr, nullptr, nullptr, out);
}